// Round 5
// baseline (318.772 us; speedup 1.0000x reference)
//
#include <hip/hip_runtime.h>
#include <hip/hip_bf16.h>

typedef short short8 __attribute__((ext_vector_type(8)));
typedef float floatx4 __attribute__((ext_vector_type(4)));

static constexpr int BATCH = 8;
static constexpr int NN    = 10000;
static constexpr int EE    = 160000;
static constexpr int EE2   = EE + NN;
static constexpr int DD    = 128;
static constexpr float SLOPE = 0.2f;
static constexpr int CAP   = 96;        // per-wave cache depth; fallback path beyond
static constexpr long OUT_ELEMS = (long)BATCH * NN * DD;
static constexpr int EB = EE / 256;     // 625 edge blocks

__device__ inline float ldf(const void* p, long i, int f32) {
    return f32 ? ((const float*)p)[i]
               : __bfloat162float(((const __hip_bfloat16*)p)[i]);
}
__device__ inline int esrc(const int* ei, int e, int i64) { return i64 ? ei[2 * e] : ei[e]; }
__device__ inline int edst(const int* ei, int e, int i64) { return i64 ? ei[2 * (EE + e)] : ei[EE + e]; }
__device__ inline short bf16bits(float v) {
    __hip_bfloat16 b = __float2bfloat16(v);
    short s; __builtin_memcpy(&s, &b, 2); return s;
}
__device__ inline float b2f(short s) {
    unsigned int u = ((unsigned int)(unsigned short)s) << 16;
    float f; __builtin_memcpy(&f, &u, 4); return f;
}

// ---------------- detect dtypes + c + zero deg/lsum ----------------
__global__ __launch_bounds__(256) void k_detect(const unsigned short* __restrict__ xu,
                                                const int* __restrict__ ei,
                                                const void* __restrict__ We,
                                                const void* __restrict__ att_edge,
                                                int* __restrict__ flags,
                                                float* __restrict__ cout,
                                                int* __restrict__ deg,
                                                float* __restrict__ lsum) {
    int t = threadIdx.x;
    if (blockIdx.x > 0) {
        int idx = (blockIdx.x - 1) * 256 + t;
        if (idx < NN) { deg[idx] = 0; lsum[idx] = 0.f; }
        return;
    }
    __shared__ int cnt[2];
    __shared__ float red[256];
    if (t < 2) cnt[t] = 0;
    __syncthreads();
    int c1 = 0;
    for (int i = t; i < 32768; i += 256) {
        unsigned short u = xu[i];
        if ((u & 0x7F80u) == 0x7F80u) c1++;
    }
    int c2 = (ei[2 * t + 1] != 0) ? 1 : 0;
    if (c1) atomicAdd(&cnt[0], c1);
    if (c2) atomicAdd(&cnt[1], c2);
    __syncthreads();
    int f32 = (cnt[0] > 0);
    if (t == 0) { flags[0] = f32; flags[1] = (cnt[1] == 0); }
    red[t] = (t < DD) ? ldf(We, t, f32) * ldf(att_edge, t, f32) : 0.f;
    __syncthreads();
    for (int o = 128; o > 0; o >>= 1) {
        if (t < o) red[t] += red[t + o];
        __syncthreads();
    }
    if (t == 0) *cout = red[0];
}

// ---------------- deg/lsum atomics + W->bf16 conversion tail ----------------
__global__ __launch_bounds__(256) void k_deg(const int* __restrict__ ei,
                                             const void* __restrict__ attr,
                                             const void* __restrict__ W,
                                             const int* __restrict__ flags,
                                             int* __restrict__ deg, float* __restrict__ lsum,
                                             __hip_bfloat16* __restrict__ Wb) {
    int f32 = flags[0], i64 = flags[1];
    int bId = blockIdx.x, t = threadIdx.x;
    if (bId < EB) {
        int e = bId * 256 + t;
        int d = edst(ei, e, i64);
        atomicAdd(&deg[d], 1);
        atomicAdd(&lsum[d], ldf(attr, e, f32));
    } else {
        int idx = (bId - EB) * 512 + t * 2;
        if (f32) {
            float2 v = ((const float2*)W)[idx >> 1];
            Wb[idx]     = __float2bfloat16(v.x);
            Wb[idx + 1] = __float2bfloat16(v.y);
        } else {
            ((ushort2*)Wb)[idx >> 1] = ((const ushort2*)W)[idx >> 1];
        }
    }
}

// ---------------- h = x @ W^T (+ transposed a_src/a_dst epilogue) ----------------
template<int F32>
__device__ inline void load_a(const void* __restrict__ x, long row, int quad, short8 afr[4]) {
    if (F32) {
        const float* xr = (const float*)x + row * DD;
        #pragma unroll
        for (int kk = 0; kk < 4; kk++) {
            const float* p = xr + kk * 32 + quad * 8;
            short8 a;
            #pragma unroll
            for (int j = 0; j < 8; j++) a[j] = bf16bits(p[j]);
            afr[kk] = a;
        }
    } else {
        const short* xr = (const short*)x + row * DD;
        #pragma unroll
        for (int kk = 0; kk < 4; kk++)
            afr[kk] = *(const short8*)(xr + kk * 32 + quad * 8);
    }
}

__global__ __launch_bounds__(128) void k_gemm(const void* __restrict__ x,
                                              const __hip_bfloat16* __restrict__ Wb,
                                              const void* __restrict__ att_src,
                                              const void* __restrict__ att_dst,
                                              const int* __restrict__ flags,
                                              __hip_bfloat16* __restrict__ h,
                                              float* __restrict__ asrc_t, float* __restrict__ adst_t) {
    __shared__ float tile[2][16 * 132];
    int f32 = flags[0];
    int wave = threadIdx.x >> 6;
    int lane = threadIdx.x & 63;
    int l15  = lane & 15, quad = lane >> 4;
    long rows_base = (long)blockIdx.x * 32 + wave * 16;

    short8 afr[4];
    if (f32) load_a<1>(x, rows_base + l15, quad, afr);
    else     load_a<0>(x, rows_base + l15, quad, afr);

    const short* wr = (const short*)Wb;
    floatx4 acc[8];
    #pragma unroll
    for (int jt = 0; jt < 8; jt++) acc[jt] = (floatx4){0.f, 0.f, 0.f, 0.f};
    #pragma unroll
    for (int jt = 0; jt < 8; jt++) {
        #pragma unroll
        for (int kk = 0; kk < 4; kk++) {
            short8 bfr = *(const short8*)(wr + (jt * 16 + l15) * DD + kk * 32 + quad * 8);
            acc[jt] = __builtin_amdgcn_mfma_f32_16x16x32_bf16(afr[kk], bfr, acc[jt], 0, 0, 0);
        }
    }

    float asum[4] = {0.f, 0.f, 0.f, 0.f};
    float dsum[4] = {0.f, 0.f, 0.f, 0.f};
    #pragma unroll
    for (int jt = 0; jt < 8; jt++) {
        int col = jt * 16 + l15;
        float as = ldf(att_src, col, f32);
        float ad = ldf(att_dst, col, f32);
        #pragma unroll
        for (int r = 0; r < 4; r++) {
            asum[r] += acc[jt][r] * as;
            dsum[r] += acc[jt][r] * ad;
        }
    }
    #pragma unroll
    for (int r = 0; r < 4; r++) {
        float a = asum[r], d = dsum[r];
        #pragma unroll
        for (int o = 1; o < 16; o <<= 1) { a += __shfl_xor(a, o, 64); d += __shfl_xor(d, o, 64); }
        if (l15 == 0) {
            long row = rows_base + quad * 4 + r;
            int b = (int)(row / NN), n = (int)(row - (long)b * NN);
            asrc_t[n * 8 + b] = a;
            adst_t[n * 8 + b] = d;
        }
    }

    float* tl = &tile[wave][0];
    #pragma unroll
    for (int jt = 0; jt < 8; jt++)
        #pragma unroll
        for (int r = 0; r < 4; r++)
            tl[(quad * 4 + r) * 132 + jt * 16 + l15] = acc[jt][r];
    short* hp = (short*)h;
    #pragma unroll
    for (int it = 0; it < 4; it++) {
        int row = it * 4 + quad;
        float4 f0 = *(const float4*)&tl[row * 132 + l15 * 8];
        float4 f1 = *(const float4*)&tl[row * 132 + l15 * 8 + 4];
        short8 o;
        o[0] = bf16bits(f0.x); o[1] = bf16bits(f0.y); o[2] = bf16bits(f0.z); o[3] = bf16bits(f0.w);
        o[4] = bf16bits(f1.x); o[5] = bf16bits(f1.y); o[6] = bf16bits(f1.z); o[7] = bf16bits(f1.w);
        *(short8*)(hp + (rows_base + row) * DD + l15 * 8) = o;
    }
}

// ---------------- exclusive scan ----------------
__global__ __launch_bounds__(1024) void k_scan(const int* __restrict__ deg, int* __restrict__ offs) {
    __shared__ int part[1024];
    int t = threadIdx.x;
    const int PER = (NN + 1023) / 1024;
    int base = t * PER;
    int s = 0;
    for (int i = 0; i < PER; i++) { int idx = base + i; if (idx < NN) s += deg[idx]; }
    part[t] = s;
    __syncthreads();
    for (int o = 1; o < 1024; o <<= 1) {
        int v = (t >= o) ? part[t - o] : 0;
        __syncthreads();
        part[t] += v;
        __syncthreads();
    }
    int run = (t == 0) ? 0 : part[t - 1];
    for (int i = 0; i < PER; i++) {
        int idx = base + i;
        if (idx < NN) { offs[idx] = run; run += deg[idx]; }
    }
    if (t == 1023) offs[NN] = run;
}

// ---------------- CSR fill: also materialize srcs + attrs in CSR order ----------------
__global__ __launch_bounds__(256) void k_fill(const int* __restrict__ ei,
                                              const void* __restrict__ attr,
                                              const int* __restrict__ flags,
                                              int* __restrict__ offs, int* __restrict__ eids,
                                              int* __restrict__ srcs, float* __restrict__ attrs) {
    int f32 = flags[0], i64 = flags[1];
    int e = blockIdx.x * 256 + threadIdx.x;
    if (e < EE) {
        int d = edst(ei, e, i64);
        int s = esrc(ei, e, i64);
        float at = ldf(attr, e, f32);
        int p = atomicAdd(&offs[d], 1);
        eids[p] = e;
        srcs[p] = s;
        attrs[p] = at;
    }
}

// ---------------- alpha: one wave per node, all 8 batches (lanes = 8 edges x 8 batches) ----------------
__global__ __launch_bounds__(256) void k_alpha(const int* __restrict__ eids,
                                               const int* __restrict__ srcs,
                                               const float* __restrict__ attrs,
                                               const float* __restrict__ asrc_t,
                                               const float* __restrict__ adst_t,
                                               const int* __restrict__ deg,
                                               const float* __restrict__ lsum,
                                               const int* __restrict__ offs,
                                               const float* __restrict__ cptr,
                                               const int* __restrict__ flags,
                                               float* __restrict__ alph,       // [8][EE] CSR order
                                               float* __restrict__ alph_self,  // [8][NN]
                                               void* __restrict__ outbuf) {
    __shared__ float s_ex[4][CAP][8];
    int f32 = flags[0];
    int wv = threadIdx.x >> 6, lane = threadIdx.x & 63;
    int n = blockIdx.x * 4 + wv;
    int il = lane >> 3, bl = lane & 7;

    float c  = *cptr;
    int   dg = deg[n];
    int   off = offs[n] - dg;
    int   cnt = dg + 1;
    float lattr = lsum[n] / fmaxf((float)dg, 1.0f);
    float an = adst_t[n * 8 + bl];

    float psum = 0.f;
    for (int base = 0; base < cnt; base += 8) {
        int i = base + il;
        if (i < cnt) {
            int s; float at;
            if (i < dg) { s = srcs[off + i]; at = attrs[off + i]; }
            else        { s = n; at = lattr; }
            float a = asrc_t[s * 8 + bl] + an + c * at;
            a = (a > 0.f) ? a : SLOPE * a;
            float ex = __expf(a);
            if (i < CAP) s_ex[wv][i][bl] = ex;
            psum += ex;
        }
    }
    psum += __shfl_xor(psum, 8, 64);
    psum += __shfl_xor(psum, 16, 64);
    psum += __shfl_xor(psum, 32, 64);
    float inv = 1.0f / (psum + 1e-16f);

    for (int base = 0; base < cnt; base += 8) {
        int i = base + il;
        if (i < cnt) {
            float ex;
            if (i < CAP) ex = s_ex[wv][i][bl];
            else {
                int s; float at;
                if (i < dg) { s = srcs[off + i]; at = attrs[off + i]; }
                else        { s = n; at = lattr; }
                float a = asrc_t[s * 8 + bl] + an + c * at;
                a = (a > 0.f) ? a : SLOPE * a;
                ex = __expf(a);
            }
            float al = ex * inv;
            long gidx;
            if (i < dg) {
                alph[(long)bl * EE + off + i] = al;
                gidx = OUT_ELEMS + (long)bl * EE2 + eids[off + i];
            } else {
                alph_self[bl * NN + n] = al;
                gidx = OUT_ELEMS + (long)bl * EE2 + EE + n;
            }
            if (f32) ((float*)outbuf)[gidx] = al;
            else     ((__hip_bfloat16*)outbuf)[gidx] = __float2bfloat16(al);
        }
    }
}

// ---------------- agg: per (b,n) wave, XCD-pinned; coalesced alpha/src; dual 4-edge pipeline ----------------
__global__ __launch_bounds__(256) void k_agg(const int* __restrict__ srcs,
                                             const float* __restrict__ alph,
                                             const float* __restrict__ alph_self,
                                             const __hip_bfloat16* __restrict__ h,
                                             const int* __restrict__ deg,
                                             const int* __restrict__ offs,
                                             const void* __restrict__ bias,
                                             const int* __restrict__ flags,
                                             void* __restrict__ outbuf) {
    __shared__ int   s_s[4][CAP];
    __shared__ float s_al[4][CAP];
    int f32 = flags[0];
    int wv = threadIdx.x >> 6, lane = threadIdx.x & 63;
    int b = blockIdx.x & 7;                       // XCD-pin: one batch per XCD
    int n = (blockIdx.x >> 3) * 4 + wv;

    int dg = deg[n];
    int off = offs[n] - dg;
    int cnt = dg + 1;
    const float* alph_b = alph + (long)b * EE;

    for (int i = lane; i < cnt && i < CAP; i += 64) {
        s_s[wv][i]  = (i < dg) ? srcs[off + i]   : n;
        s_al[wv][i] = (i < dg) ? alph_b[off + i] : alph_self[b * NN + n];
    }

    int g = lane >> 4, c16 = lane & 15;
    const short* hb = (const short*)h + (long)b * NN * DD;
    float acc[8];
    #pragma unroll
    for (int j = 0; j < 8; j++) acc[j] = 0.f;

    for (int base = 0; base < cnt; base += 8) {
        int ia = base + g, ib = base + 4 + g;
        short8 va = {}, vb = {};
        float ala = 0.f, alb = 0.f;
        if (ia < cnt) {
            int s;
            if (ia < CAP) { s = s_s[wv][ia]; ala = s_al[wv][ia]; }
            else { s = (ia < dg) ? srcs[off + ia] : n;
                   ala = (ia < dg) ? alph_b[off + ia] : alph_self[b * NN + n]; }
            va = *(const short8*)(hb + (long)s * DD + c16 * 8);
        }
        if (ib < cnt) {
            int s;
            if (ib < CAP) { s = s_s[wv][ib]; alb = s_al[wv][ib]; }
            else { s = (ib < dg) ? srcs[off + ib] : n;
                   alb = (ib < dg) ? alph_b[off + ib] : alph_self[b * NN + n]; }
            vb = *(const short8*)(hb + (long)s * DD + c16 * 8);
        }
        if (ia < cnt) {
            #pragma unroll
            for (int j = 0; j < 8; j++) acc[j] += ala * b2f(va[j]);
        }
        if (ib < cnt) {
            #pragma unroll
            for (int j = 0; j < 8; j++) acc[j] += alb * b2f(vb[j]);
        }
    }
    #pragma unroll
    for (int j = 0; j < 8; j++) {
        acc[j] += __shfl_xor(acc[j], 16, 64);
        acc[j] += __shfl_xor(acc[j], 32, 64);
    }
    #pragma unroll
    for (int j = 0; j < 8; j++) acc[j] += ldf(bias, c16 * 8 + j, f32);

    if (g == 0) {
        long row = (long)b * NN + n;
        if (f32) {
            float4 lo = {acc[0], acc[1], acc[2], acc[3]};
            float4 hi = {acc[4], acc[5], acc[6], acc[7]};
            float4* orow = (float4*)((float*)outbuf + row * DD);
            orow[c16 * 2]     = lo;
            orow[c16 * 2 + 1] = hi;
        } else {
            short8 o;
            #pragma unroll
            for (int j = 0; j < 8; j++) o[j] = bf16bits(acc[j]);
            ((short8*)((__hip_bfloat16*)outbuf + row * DD))[c16] = o;
        }
    }
}

extern "C" void kernel_launch(void* const* d_in, const int* in_sizes, int n_in,
                              void* d_out, int out_size, void* d_ws, size_t ws_size,
                              hipStream_t stream) {
    const void* x        = d_in[0];
    const int*  ei       = (const int*)d_in[1];
    const void* attr     = d_in[2];
    const void* W        = d_in[3];
    const void* We       = d_in[4];
    const void* att_src  = d_in[5];
    const void* att_dst  = d_in[6];
    const void* att_edge = d_in[7];
    const void* bias     = d_in[8];

    char* ws = (char*)d_ws;
    size_t off = 0;
    auto alloc = [&](size_t bytes) { size_t o = off; off = (off + bytes + 255) & ~(size_t)255; return o; };
    __hip_bfloat16* h    = (__hip_bfloat16*)(ws + alloc((size_t)BATCH * NN * DD * 2));
    float* asrc_t        = (float*)(ws + alloc((size_t)NN * 8 * 4));
    float* adst_t        = (float*)(ws + alloc((size_t)NN * 8 * 4));
    int*   deg           = (int*)  (ws + alloc((size_t)NN * 4));
    float* lsum          = (float*)(ws + alloc((size_t)NN * 4));
    int*   offs          = (int*)  (ws + alloc((size_t)(NN + 1) * 4));
    int*   eids          = (int*)  (ws + alloc((size_t)EE * 4));
    int*   srcs          = (int*)  (ws + alloc((size_t)EE * 4));
    float* attrs         = (float*)(ws + alloc((size_t)EE * 4));
    float* alph          = (float*)(ws + alloc((size_t)BATCH * EE * 4));
    float* alph_self     = (float*)(ws + alloc((size_t)BATCH * NN * 4));
    __hip_bfloat16* Wb   = (__hip_bfloat16*)(ws + alloc((size_t)DD * DD * 2));
    float* cscal         = (float*)(ws + alloc(256));
    int*   flags         = (int*)  (ws + alloc(256));

    k_detect<<<41, 256, 0, stream>>>((const unsigned short*)x, ei, We, att_edge,
                                     flags, cscal, deg, lsum);
    k_deg   <<<EB + 32, 256, 0, stream>>>(ei, attr, W, flags, deg, lsum, Wb);
    k_gemm  <<<(BATCH * NN) / 32, 128, 0, stream>>>(x, Wb, att_src, att_dst, flags,
                                                    h, asrc_t, adst_t);
    k_scan  <<<1, 1024, 0, stream>>>(deg, offs);
    k_fill  <<<EB, 256, 0, stream>>>(ei, attr, flags, offs, eids, srcs, attrs);
    k_alpha <<<NN / 4, 256, 0, stream>>>(eids, srcs, attrs, asrc_t, adst_t, deg, lsum,
                                         offs, cscal, flags, alph, alph_self, d_out);
    k_agg   <<<(BATCH * NN) / 4, 256, 0, stream>>>(srcs, alph, alph_self, h, deg, offs,
                                                   bias, flags, d_out);
}

// Round 6
// 272.188 us; speedup vs baseline: 1.1712x; 1.1712x over previous
//
#include <hip/hip_runtime.h>
#include <hip/hip_bf16.h>

typedef short short8 __attribute__((ext_vector_type(8)));
typedef float floatx4 __attribute__((ext_vector_type(4)));

static constexpr int BATCH = 8;
static constexpr int NN    = 10000;
static constexpr int EE    = 160000;
static constexpr int EE2   = EE + NN;
static constexpr int DD    = 128;
static constexpr float SLOPE = 0.2f;
static constexpr int CAP   = 96;        // k_alpha LDS cache depth; fallback beyond
static constexpr long OUT_ELEMS = (long)BATCH * NN * DD;
static constexpr int EB = EE / 256;     // 625 edge blocks

__device__ inline float ldf(const void* p, long i, int f32) {
    return f32 ? ((const float*)p)[i]
               : __bfloat162float(((const __hip_bfloat16*)p)[i]);
}
__device__ inline int esrc(const int* ei, int e, int i64) { return i64 ? ei[2 * e] : ei[e]; }
__device__ inline int edst(const int* ei, int e, int i64) { return i64 ? ei[2 * (EE + e)] : ei[EE + e]; }
__device__ inline short bf16bits(float v) {
    __hip_bfloat16 b = __float2bfloat16(v);
    short s; __builtin_memcpy(&s, &b, 2); return s;
}

// ---------------- detect dtypes + c + zero deg/lsum ----------------
__global__ __launch_bounds__(256) void k_detect(const unsigned short* __restrict__ xu,
                                                const int* __restrict__ ei,
                                                const void* __restrict__ We,
                                                const void* __restrict__ att_edge,
                                                int* __restrict__ flags,
                                                float* __restrict__ cout,
                                                int* __restrict__ deg,
                                                float* __restrict__ lsum) {
    int t = threadIdx.x;
    if (blockIdx.x > 0) {
        int idx = (blockIdx.x - 1) * 256 + t;
        if (idx < NN) { deg[idx] = 0; lsum[idx] = 0.f; }
        return;
    }
    __shared__ int cnt[2];
    __shared__ float red[256];
    if (t < 2) cnt[t] = 0;
    __syncthreads();
    int c1 = 0;
    for (int i = t; i < 32768; i += 256) {
        unsigned short u = xu[i];
        if ((u & 0x7F80u) == 0x7F80u) c1++;
    }
    int c2 = (ei[2 * t + 1] != 0) ? 1 : 0;
    if (c1) atomicAdd(&cnt[0], c1);
    if (c2) atomicAdd(&cnt[1], c2);
    __syncthreads();
    int f32 = (cnt[0] > 0);
    if (t == 0) { flags[0] = f32; flags[1] = (cnt[1] == 0); }
    red[t] = (t < DD) ? ldf(We, t, f32) * ldf(att_edge, t, f32) : 0.f;
    __syncthreads();
    for (int o = 128; o > 0; o >>= 1) {
        if (t < o) red[t] += red[t + o];
        __syncthreads();
    }
    if (t == 0) *cout = red[0];
}

// ---------------- deg/lsum atomics + W->bf16 conversion tail ----------------
__global__ __launch_bounds__(256) void k_deg(const int* __restrict__ ei,
                                             const void* __restrict__ attr,
                                             const void* __restrict__ W,
                                             const int* __restrict__ flags,
                                             int* __restrict__ deg, float* __restrict__ lsum,
                                             __hip_bfloat16* __restrict__ Wb) {
    int f32 = flags[0], i64 = flags[1];
    int bId = blockIdx.x, t = threadIdx.x;
    if (bId < EB) {
        int e = bId * 256 + t;
        int d = edst(ei, e, i64);
        atomicAdd(&deg[d], 1);
        atomicAdd(&lsum[d], ldf(attr, e, f32));
    } else {
        int idx = (bId - EB) * 512 + t * 2;
        if (f32) {
            float2 v = ((const float2*)W)[idx >> 1];
            Wb[idx]     = __float2bfloat16(v.x);
            Wb[idx + 1] = __float2bfloat16(v.y);
        } else {
            ((ushort2*)Wb)[idx >> 1] = ((const ushort2*)W)[idx >> 1];
        }
    }
}

// ---------------- h = x @ W^T (+ transposed a_src/a_dst epilogue) ----------------
template<int F32>
__device__ inline void load_a(const void* __restrict__ x, long row, int quad, short8 afr[4]) {
    if (F32) {
        const float* xr = (const float*)x + row * DD;
        #pragma unroll
        for (int kk = 0; kk < 4; kk++) {
            const float* p = xr + kk * 32 + quad * 8;
            short8 a;
            #pragma unroll
            for (int j = 0; j < 8; j++) a[j] = bf16bits(p[j]);
            afr[kk] = a;
        }
    } else {
        const short* xr = (const short*)x + row * DD;
        #pragma unroll
        for (int kk = 0; kk < 4; kk++)
            afr[kk] = *(const short8*)(xr + kk * 32 + quad * 8);
    }
}

__global__ __launch_bounds__(128) void k_gemm(const void* __restrict__ x,
                                              const __hip_bfloat16* __restrict__ Wb,
                                              const void* __restrict__ att_src,
                                              const void* __restrict__ att_dst,
                                              const int* __restrict__ flags,
                                              __hip_bfloat16* __restrict__ h,
                                              float* __restrict__ asrc_t, float* __restrict__ adst_t) {
    __shared__ float tile[2][16 * 132];
    int f32 = flags[0];
    int wave = threadIdx.x >> 6;
    int lane = threadIdx.x & 63;
    int l15  = lane & 15, quad = lane >> 4;
    long rows_base = (long)blockIdx.x * 32 + wave * 16;

    short8 afr[4];
    if (f32) load_a<1>(x, rows_base + l15, quad, afr);
    else     load_a<0>(x, rows_base + l15, quad, afr);

    const short* wr = (const short*)Wb;
    floatx4 acc[8];
    #pragma unroll
    for (int jt = 0; jt < 8; jt++) acc[jt] = (floatx4){0.f, 0.f, 0.f, 0.f};
    #pragma unroll
    for (int jt = 0; jt < 8; jt++) {
        #pragma unroll
        for (int kk = 0; kk < 4; kk++) {
            short8 bfr = *(const short8*)(wr + (jt * 16 + l15) * DD + kk * 32 + quad * 8);
            acc[jt] = __builtin_amdgcn_mfma_f32_16x16x32_bf16(afr[kk], bfr, acc[jt], 0, 0, 0);
        }
    }

    float asum[4] = {0.f, 0.f, 0.f, 0.f};
    float dsum[4] = {0.f, 0.f, 0.f, 0.f};
    #pragma unroll
    for (int jt = 0; jt < 8; jt++) {
        int col = jt * 16 + l15;
        float as = ldf(att_src, col, f32);
        float ad = ldf(att_dst, col, f32);
        #pragma unroll
        for (int r = 0; r < 4; r++) {
            asum[r] += acc[jt][r] * as;
            dsum[r] += acc[jt][r] * ad;
        }
    }
    #pragma unroll
    for (int r = 0; r < 4; r++) {
        float a = asum[r], d = dsum[r];
        #pragma unroll
        for (int o = 1; o < 16; o <<= 1) { a += __shfl_xor(a, o, 64); d += __shfl_xor(d, o, 64); }
        if (l15 == 0) {
            long row = rows_base + quad * 4 + r;
            int b = (int)(row / NN), n = (int)(row - (long)b * NN);
            asrc_t[n * 8 + b] = a;
            adst_t[n * 8 + b] = d;
        }
    }

    float* tl = &tile[wave][0];
    #pragma unroll
    for (int jt = 0; jt < 8; jt++)
        #pragma unroll
        for (int r = 0; r < 4; r++)
            tl[(quad * 4 + r) * 132 + jt * 16 + l15] = acc[jt][r];
    short* hp = (short*)h;
    #pragma unroll
    for (int it = 0; it < 4; it++) {
        int row = it * 4 + quad;
        float4 f0 = *(const float4*)&tl[row * 132 + l15 * 8];
        float4 f1 = *(const float4*)&tl[row * 132 + l15 * 8 + 4];
        short8 o;
        o[0] = bf16bits(f0.x); o[1] = bf16bits(f0.y); o[2] = bf16bits(f0.z); o[3] = bf16bits(f0.w);
        o[4] = bf16bits(f1.x); o[5] = bf16bits(f1.y); o[6] = bf16bits(f1.z); o[7] = bf16bits(f1.w);
        *(short8*)(hp + (rows_base + row) * DD + l15 * 8) = o;
    }
}

// ---------------- exclusive scan ----------------
__global__ __launch_bounds__(1024) void k_scan(const int* __restrict__ deg, int* __restrict__ offs) {
    __shared__ int part[1024];
    int t = threadIdx.x;
    const int PER = (NN + 1023) / 1024;
    int base = t * PER;
    int s = 0;
    for (int i = 0; i < PER; i++) { int idx = base + i; if (idx < NN) s += deg[idx]; }
    part[t] = s;
    __syncthreads();
    for (int o = 1; o < 1024; o <<= 1) {
        int v = (t >= o) ? part[t - o] : 0;
        __syncthreads();
        part[t] += v;
        __syncthreads();
    }
    int run = (t == 0) ? 0 : part[t - 1];
    for (int i = 0; i < PER; i++) {
        int idx = base + i;
        if (idx < NN) { offs[idx] = run; run += deg[idx]; }
    }
    if (t == 1023) offs[NN] = run;
}

// ---------------- CSR fill: srcs/attrs in CSR order + pos[e] (CSR slot of edge e) ----------------
__global__ __launch_bounds__(256) void k_fill(const int* __restrict__ ei,
                                              const void* __restrict__ attr,
                                              const int* __restrict__ flags,
                                              int* __restrict__ offs,
                                              int* __restrict__ srcs, float* __restrict__ attrs,
                                              int* __restrict__ pos) {
    int f32 = flags[0], i64 = flags[1];
    int e = blockIdx.x * 256 + threadIdx.x;
    if (e < EE) {
        int d = edst(ei, e, i64);
        int s = esrc(ei, e, i64);
        float at = ldf(attr, e, f32);
        int p = atomicAdd(&offs[d], 1);
        srcs[p] = s;
        attrs[p] = at;
        pos[e] = p;
    }
}

// ---------------- alpha: one wave per node, 8 edges x 8 batches; coalesced alph writes ----------------
__global__ __launch_bounds__(256) void k_alpha(const int* __restrict__ srcs,
                                               const float* __restrict__ attrs,
                                               const float* __restrict__ asrc_t,
                                               const float* __restrict__ adst_t,
                                               const int* __restrict__ deg,
                                               const float* __restrict__ lsum,
                                               const int* __restrict__ offs,
                                               const float* __restrict__ cptr,
                                               float* __restrict__ alph,       // [EE][8] CSR-major
                                               float* __restrict__ alph_self) { // [NN][8]
    __shared__ float s_ex[4][CAP][8];
    int wv = threadIdx.x >> 6, lane = threadIdx.x & 63;
    int n = blockIdx.x * 4 + wv;
    int il = lane >> 3, bl = lane & 7;

    float c  = *cptr;
    int   dg = deg[n];
    int   off = offs[n] - dg;
    int   cnt = dg + 1;
    float lattr = lsum[n] / fmaxf((float)dg, 1.0f);
    float an = adst_t[n * 8 + bl];

    float psum = 0.f;
    for (int base = 0; base < cnt; base += 8) {
        int i = base + il;
        if (i < cnt) {
            int s; float at;
            if (i < dg) { s = srcs[off + i]; at = attrs[off + i]; }
            else        { s = n; at = lattr; }
            float a = asrc_t[s * 8 + bl] + an + c * at;
            a = (a > 0.f) ? a : SLOPE * a;
            float ex = __expf(a);
            if (i < CAP) s_ex[wv][i][bl] = ex;
            psum += ex;
        }
    }
    psum += __shfl_xor(psum, 8, 64);
    psum += __shfl_xor(psum, 16, 64);
    psum += __shfl_xor(psum, 32, 64);
    float inv = 1.0f / (psum + 1e-16f);

    for (int base = 0; base < cnt; base += 8) {
        int i = base + il;
        if (i < cnt) {
            float ex;
            if (i < CAP) ex = s_ex[wv][i][bl];
            else {
                int s; float at;
                if (i < dg) { s = srcs[off + i]; at = attrs[off + i]; }
                else        { s = n; at = lattr; }
                float a = asrc_t[s * 8 + bl] + an + c * at;
                a = (a > 0.f) ? a : SLOPE * a;
                ex = __expf(a);
            }
            float al = ex * inv;
            if (i < dg) alph[(long)(off + i) * 8 + bl] = al;
            else        alph_self[(long)n * 8 + bl] = al;
        }
    }
}

// ---------------- agg: quad-per-(b,n); no LDS, no reductions; XCD-pinned batch ----------------
__global__ __launch_bounds__(256) void k_agg(const int* __restrict__ srcs,
                                             const float* __restrict__ alph,
                                             const float* __restrict__ alph_self,
                                             const __hip_bfloat16* __restrict__ h,
                                             const int* __restrict__ deg,
                                             const int* __restrict__ offs,
                                             const void* __restrict__ bias,
                                             const int* __restrict__ flags,
                                             void* __restrict__ outbuf) {
    int f32 = flags[0];
    int tid = threadIdx.x;
    int g   = (tid & 63) >> 4;              // quad within wave
    int c16 = tid & 15;
    int wv  = tid >> 6;
    int b = blockIdx.x & 7;                 // XCD-pin: one batch per XCD
    int n = (blockIdx.x >> 3) * 16 + wv * 4 + g;

    int dg  = deg[n];
    int off = offs[n] - dg;
    int cnt = dg + 1;

    const unsigned short* hb = (const unsigned short*)h + (long)b * NN * DD;
    float acc[8];
    #pragma unroll
    for (int j = 0; j < 8; j++) acc[j] = 0.f;

    // 2-deep pipeline over this quad's edge list
    uint4 hv0 = {0, 0, 0, 0};
    float al0 = 0.f;
    {
        int s0;
        if (0 < dg) { s0 = srcs[off]; al0 = alph[(long)off * 8 + b]; }
        else        { s0 = n;         al0 = alph_self[(long)n * 8 + b]; }
        hv0 = *(const uint4*)(hb + (long)s0 * DD + c16 * 8);
    }
    for (int i = 0; i < cnt; i++) {
        uint4 hv1 = {0, 0, 0, 0};
        float al1 = 0.f;
        int i1 = i + 1;
        if (i1 < cnt) {
            int s1;
            if (i1 < dg) { s1 = srcs[off + i1]; al1 = alph[(long)(off + i1) * 8 + b]; }
            else         { s1 = n;              al1 = alph_self[(long)n * 8 + b]; }
            hv1 = *(const uint4*)(hb + (long)s1 * DD + c16 * 8);
        }
        acc[0] += al0 * __uint_as_float(hv0.x << 16);
        acc[1] += al0 * __uint_as_float(hv0.x & 0xFFFF0000u);
        acc[2] += al0 * __uint_as_float(hv0.y << 16);
        acc[3] += al0 * __uint_as_float(hv0.y & 0xFFFF0000u);
        acc[4] += al0 * __uint_as_float(hv0.z << 16);
        acc[5] += al0 * __uint_as_float(hv0.z & 0xFFFF0000u);
        acc[6] += al0 * __uint_as_float(hv0.w << 16);
        acc[7] += al0 * __uint_as_float(hv0.w & 0xFFFF0000u);
        hv0 = hv1; al0 = al1;
    }
    #pragma unroll
    for (int j = 0; j < 8; j++) acc[j] += ldf(bias, c16 * 8 + j, f32);

    long row = (long)b * NN + n;
    if (f32) {
        float4 lo = {acc[0], acc[1], acc[2], acc[3]};
        float4 hi = {acc[4], acc[5], acc[6], acc[7]};
        float4* orow = (float4*)((float*)outbuf + row * DD);
        orow[c16 * 2]     = lo;
        orow[c16 * 2 + 1] = hi;
    } else {
        short8 o;
        #pragma unroll
        for (int j = 0; j < 8; j++) o[j] = bf16bits(acc[j]);
        ((short8*)((__hip_bfloat16*)outbuf + row * DD))[c16] = o;
    }
}

// ---------------- attn: edge order; scattered L2 reads of alph, coalesced writes ----------------
__global__ __launch_bounds__(256) void k_attn(const int* __restrict__ pos,
                                              const float* __restrict__ alph,
                                              const float* __restrict__ alph_self,
                                              const int* __restrict__ flags,
                                              void* __restrict__ outbuf) {
    int f32 = flags[0];
    int e2 = blockIdx.x * 256 + threadIdx.x;
    if (e2 >= EE2) return;
    const float* src8;
    if (e2 < EE) src8 = alph + (long)pos[e2] * 8;
    else         src8 = alph_self + (long)(e2 - EE) * 8;
    float4 lo = *(const float4*)src8;
    float4 hi = *(const float4*)(src8 + 4);
    float v[8] = {lo.x, lo.y, lo.z, lo.w, hi.x, hi.y, hi.z, hi.w};
    #pragma unroll
    for (int b = 0; b < BATCH; b++) {
        long gidx = OUT_ELEMS + (long)b * EE2 + e2;
        if (f32) ((float*)outbuf)[gidx] = v[b];
        else     ((__hip_bfloat16*)outbuf)[gidx] = __float2bfloat16(v[b]);
    }
}

extern "C" void kernel_launch(void* const* d_in, const int* in_sizes, int n_in,
                              void* d_out, int out_size, void* d_ws, size_t ws_size,
                              hipStream_t stream) {
    const void* x        = d_in[0];
    const int*  ei       = (const int*)d_in[1];
    const void* attr     = d_in[2];
    const void* W        = d_in[3];
    const void* We       = d_in[4];
    const void* att_src  = d_in[5];
    const void* att_dst  = d_in[6];
    const void* att_edge = d_in[7];
    const void* bias     = d_in[8];

    char* ws = (char*)d_ws;
    size_t off = 0;
    auto alloc = [&](size_t bytes) { size_t o = off; off = (off + bytes + 255) & ~(size_t)255; return o; };
    __hip_bfloat16* h    = (__hip_bfloat16*)(ws + alloc((size_t)BATCH * NN * DD * 2));
    float* asrc_t        = (float*)(ws + alloc((size_t)NN * 8 * 4));
    float* adst_t        = (float*)(ws + alloc((size_t)NN * 8 * 4));
    int*   deg           = (int*)  (ws + alloc((size_t)NN * 4));
    float* lsum          = (float*)(ws + alloc((size_t)NN * 4));
    int*   offs          = (int*)  (ws + alloc((size_t)(NN + 1) * 4));
    int*   srcs          = (int*)  (ws + alloc((size_t)EE * 4));
    float* attrs         = (float*)(ws + alloc((size_t)EE * 4));
    int*   pos           = (int*)  (ws + alloc((size_t)EE * 4));
    float* alph          = (float*)(ws + alloc((size_t)EE * 8 * 4));
    float* alph_self     = (float*)(ws + alloc((size_t)NN * 8 * 4));
    __hip_bfloat16* Wb   = (__hip_bfloat16*)(ws + alloc((size_t)DD * DD * 2));
    float* cscal         = (float*)(ws + alloc(256));
    int*   flags         = (int*)  (ws + alloc(256));

    k_detect<<<41, 256, 0, stream>>>((const unsigned short*)x, ei, We, att_edge,
                                     flags, cscal, deg, lsum);
    k_deg   <<<EB + 32, 256, 0, stream>>>(ei, attr, W, flags, deg, lsum, Wb);
    k_gemm  <<<(BATCH * NN) / 32, 128, 0, stream>>>(x, Wb, att_src, att_dst, flags,
                                                    h, asrc_t, adst_t);
    k_scan  <<<1, 1024, 0, stream>>>(deg, offs);
    k_fill  <<<EB, 256, 0, stream>>>(ei, attr, flags, offs, srcs, attrs, pos);
    k_alpha <<<NN / 4, 256, 0, stream>>>(srcs, attrs, asrc_t, adst_t, deg, lsum,
                                         offs, cscal, alph, alph_self);
    k_agg   <<<(BATCH * NN) / 16, 256, 0, stream>>>(srcs, alph, alph_self, h, deg, offs,
                                                    bias, flags, d_out);
    k_attn  <<<(EE2 + 255) / 256, 256, 0, stream>>>(pos, alph, alph_self, flags, d_out);
}

// Round 7
// 254.267 us; speedup vs baseline: 1.2537x; 1.0705x over previous
//
#include <hip/hip_runtime.h>
#include <hip/hip_bf16.h>

typedef short short8 __attribute__((ext_vector_type(8)));
typedef float floatx4 __attribute__((ext_vector_type(4)));

static constexpr int BATCH = 8;
static constexpr int NN    = 10000;
static constexpr int EE    = 160000;
static constexpr int EE2   = EE + NN;
static constexpr int DD    = 128;
static constexpr float SLOPE = 0.2f;
static constexpr long OUT_ELEMS = (long)BATCH * NN * DD;
static constexpr int EB = EE / 256;     // 625 edge blocks

__device__ inline float ldf(const void* p, long i, int f32) {
    return f32 ? ((const float*)p)[i]
               : __bfloat162float(((const __hip_bfloat16*)p)[i]);
}
__device__ inline int esrc(const int* ei, int e, int i64) { return i64 ? ei[2 * e] : ei[e]; }
__device__ inline int edst(const int* ei, int e, int i64) { return i64 ? ei[2 * (EE + e)] : ei[EE + e]; }
__device__ inline short bf16bits(float v) {
    __hip_bfloat16 b = __float2bfloat16(v);
    short s; __builtin_memcpy(&s, &b, 2); return s;
}

// ---------------- detect dtypes + c + zero deg/lsum ----------------
__global__ __launch_bounds__(256) void k_detect(const unsigned short* __restrict__ xu,
                                                const int* __restrict__ ei,
                                                const void* __restrict__ We,
                                                const void* __restrict__ att_edge,
                                                int* __restrict__ flags,
                                                float* __restrict__ cout,
                                                int* __restrict__ deg,
                                                float* __restrict__ lsum) {
    int t = threadIdx.x;
    if (blockIdx.x > 0) {
        int idx = (blockIdx.x - 1) * 256 + t;
        if (idx < NN) { deg[idx] = 0; lsum[idx] = 0.f; }
        return;
    }
    __shared__ int cnt[2];
    __shared__ float red[256];
    if (t < 2) cnt[t] = 0;
    __syncthreads();
    int c1 = 0;
    for (int i = t; i < 32768; i += 256) {
        unsigned short u = xu[i];
        if ((u & 0x7F80u) == 0x7F80u) c1++;
    }
    int c2 = (ei[2 * t + 1] != 0) ? 1 : 0;
    if (c1) atomicAdd(&cnt[0], c1);
    if (c2) atomicAdd(&cnt[1], c2);
    __syncthreads();
    int f32 = (cnt[0] > 0);
    if (t == 0) { flags[0] = f32; flags[1] = (cnt[1] == 0); }
    red[t] = (t < DD) ? ldf(We, t, f32) * ldf(att_edge, t, f32) : 0.f;
    __syncthreads();
    for (int o = 128; o > 0; o >>= 1) {
        if (t < o) red[t] += red[t + o];
        __syncthreads();
    }
    if (t == 0) *cout = red[0];
}

// ---------------- deg/lsum atomics + W->bf16 conversion tail ----------------
__global__ __launch_bounds__(256) void k_deg(const int* __restrict__ ei,
                                             const void* __restrict__ attr,
                                             const void* __restrict__ W,
                                             const int* __restrict__ flags,
                                             int* __restrict__ deg, float* __restrict__ lsum,
                                             __hip_bfloat16* __restrict__ Wb) {
    int f32 = flags[0], i64 = flags[1];
    int bId = blockIdx.x, t = threadIdx.x;
    if (bId < EB) {
        int e = bId * 256 + t;
        int d = edst(ei, e, i64);
        atomicAdd(&deg[d], 1);
        atomicAdd(&lsum[d], ldf(attr, e, f32));
    } else {
        int idx = (bId - EB) * 512 + t * 2;
        if (f32) {
            float2 v = ((const float2*)W)[idx >> 1];
            Wb[idx]     = __float2bfloat16(v.x);
            Wb[idx + 1] = __float2bfloat16(v.y);
        } else {
            ((ushort2*)Wb)[idx >> 1] = ((const ushort2*)W)[idx >> 1];
        }
    }
}

// ---------------- h = x @ W^T (+ transposed a_src/a_dst epilogue) ----------------
template<int F32>
__device__ inline void load_a(const void* __restrict__ x, long row, int quad, short8 afr[4]) {
    if (F32) {
        const float* xr = (const float*)x + row * DD;
        #pragma unroll
        for (int kk = 0; kk < 4; kk++) {
            float4 f0 = *(const float4*)(xr + kk * 32 + quad * 8);
            float4 f1 = *(const float4*)(xr + kk * 32 + quad * 8 + 4);
            short8 a;
            a[0] = bf16bits(f0.x); a[1] = bf16bits(f0.y); a[2] = bf16bits(f0.z); a[3] = bf16bits(f0.w);
            a[4] = bf16bits(f1.x); a[5] = bf16bits(f1.y); a[6] = bf16bits(f1.z); a[7] = bf16bits(f1.w);
            afr[kk] = a;
        }
    } else {
        const short* xr = (const short*)x + row * DD;
        #pragma unroll
        for (int kk = 0; kk < 4; kk++)
            afr[kk] = *(const short8*)(xr + kk * 32 + quad * 8);
    }
}

__global__ __launch_bounds__(128) void k_gemm(const void* __restrict__ x,
                                              const __hip_bfloat16* __restrict__ Wb,
                                              const void* __restrict__ att_src,
                                              const void* __restrict__ att_dst,
                                              const int* __restrict__ flags,
                                              __hip_bfloat16* __restrict__ h,
                                              float* __restrict__ asrc_t, float* __restrict__ adst_t) {
    __shared__ float tile[2][16 * 132];
    int f32 = flags[0];
    int wave = threadIdx.x >> 6;
    int lane = threadIdx.x & 63;
    int l15  = lane & 15, quad = lane >> 4;
    long rows_base = (long)blockIdx.x * 32 + wave * 16;

    short8 afr[4];
    if (f32) load_a<1>(x, rows_base + l15, quad, afr);
    else     load_a<0>(x, rows_base + l15, quad, afr);

    const short* wr = (const short*)Wb;
    floatx4 acc[8];
    #pragma unroll
    for (int jt = 0; jt < 8; jt++) acc[jt] = (floatx4){0.f, 0.f, 0.f, 0.f};
    #pragma unroll
    for (int jt = 0; jt < 8; jt++) {
        #pragma unroll
        for (int kk = 0; kk < 4; kk++) {
            short8 bfr = *(const short8*)(wr + (jt * 16 + l15) * DD + kk * 32 + quad * 8);
            acc[jt] = __builtin_amdgcn_mfma_f32_16x16x32_bf16(afr[kk], bfr, acc[jt], 0, 0, 0);
        }
    }

    float asum[4] = {0.f, 0.f, 0.f, 0.f};
    float dsum[4] = {0.f, 0.f, 0.f, 0.f};
    #pragma unroll
    for (int jt = 0; jt < 8; jt++) {
        int col = jt * 16 + l15;
        float as = ldf(att_src, col, f32);
        float ad = ldf(att_dst, col, f32);
        #pragma unroll
        for (int r = 0; r < 4; r++) {
            asum[r] += acc[jt][r] * as;
            dsum[r] += acc[jt][r] * ad;
        }
    }
    #pragma unroll
    for (int r = 0; r < 4; r++) {
        float a = asum[r], d = dsum[r];
        #pragma unroll
        for (int o = 1; o < 16; o <<= 1) { a += __shfl_xor(a, o, 64); d += __shfl_xor(d, o, 64); }
        if (l15 == 0) {
            long row = rows_base + quad * 4 + r;
            int b = (int)(row / NN), n = (int)(row - (long)b * NN);
            asrc_t[n * 8 + b] = a;
            adst_t[n * 8 + b] = d;
        }
    }

    float* tl = &tile[wave][0];
    #pragma unroll
    for (int jt = 0; jt < 8; jt++)
        #pragma unroll
        for (int r = 0; r < 4; r++)
            tl[(quad * 4 + r) * 132 + jt * 16 + l15] = acc[jt][r];
    short* hp = (short*)h;
    #pragma unroll
    for (int it = 0; it < 4; it++) {
        int row = it * 4 + quad;
        float4 f0 = *(const float4*)&tl[row * 132 + l15 * 8];
        float4 f1 = *(const float4*)&tl[row * 132 + l15 * 8 + 4];
        short8 o;
        o[0] = bf16bits(f0.x); o[1] = bf16bits(f0.y); o[2] = bf16bits(f0.z); o[3] = bf16bits(f0.w);
        o[4] = bf16bits(f1.x); o[5] = bf16bits(f1.y); o[6] = bf16bits(f1.z); o[7] = bf16bits(f1.w);
        *(short8*)(hp + (rows_base + row) * DD + l15 * 8) = o;
    }
}

// ---------------- exclusive scan ----------------
__global__ __launch_bounds__(1024) void k_scan(const int* __restrict__ deg, int* __restrict__ offs) {
    __shared__ int part[1024];
    int t = threadIdx.x;
    const int PER = (NN + 1023) / 1024;
    int base = t * PER;
    int s = 0;
    for (int i = 0; i < PER; i++) { int idx = base + i; if (idx < NN) s += deg[idx]; }
    part[t] = s;
    __syncthreads();
    for (int o = 1; o < 1024; o <<= 1) {
        int v = (t >= o) ? part[t - o] : 0;
        __syncthreads();
        part[t] += v;
        __syncthreads();
    }
    int run = (t == 0) ? 0 : part[t - 1];
    for (int i = 0; i < PER; i++) {
        int idx = base + i;
        if (idx < NN) { offs[idx] = run; run += deg[idx]; }
    }
    if (t == 1023) offs[NN] = run;
}

// ---------------- CSR fill: srcs/attrs in CSR order ----------------
__global__ __launch_bounds__(256) void k_fill(const int* __restrict__ ei,
                                              const void* __restrict__ attr,
                                              const int* __restrict__ flags,
                                              int* __restrict__ offs,
                                              int* __restrict__ srcs, float* __restrict__ attrs) {
    int f32 = flags[0], i64 = flags[1];
    int e = blockIdx.x * 256 + threadIdx.x;
    if (e < EE) {
        int d = edst(ei, e, i64);
        int s = esrc(ei, e, i64);
        float at = ldf(attr, e, f32);
        int p = atomicAdd(&offs[d], 1);
        srcs[p] = s;
        attrs[p] = at;
    }
}

// ---------------- agg: quad-per-(b,n); fused exp+sum+aggregate; XCD-pinned batch ----------------
__global__ __launch_bounds__(256) void k_agg(const int* __restrict__ srcs,
                                             const float* __restrict__ attrs,
                                             const float* __restrict__ asrc_t,
                                             const float* __restrict__ adst_t,
                                             const __hip_bfloat16* __restrict__ h,
                                             const int* __restrict__ deg,
                                             const float* __restrict__ lsum,
                                             const int* __restrict__ offs,
                                             const float* __restrict__ cptr,
                                             const void* __restrict__ bias,
                                             const int* __restrict__ flags,
                                             float* __restrict__ invT,     // [NN][8]
                                             void* __restrict__ outbuf) {
    int f32 = flags[0];
    int tid = threadIdx.x;
    int g   = (tid & 63) >> 4;              // quad within wave
    int c16 = tid & 15;
    int wv  = tid >> 6;
    int b = blockIdx.x & 7;                 // XCD-pin: one batch per XCD
    int n = (blockIdx.x >> 3) * 16 + wv * 4 + g;

    float c   = *cptr;
    int dg    = deg[n];
    int off   = offs[n] - dg;               // offs advanced by k_fill
    int cnt   = dg + 1;
    float lattr = lsum[n] / fmaxf((float)dg, 1.0f);
    float an  = adst_t[n * 8 + b];

    const unsigned short* hb = (const unsigned short*)h + (long)b * NN * DD;
    float acc[8];
    #pragma unroll
    for (int j = 0; j < 8; j++) acc[j] = 0.f;
    float ssum = 0.f;

    // 2-pair prefetch pipeline: up to 4 h-loads + 4 asrc-loads in flight
    uint4 hvA = {0,0,0,0}, hvB = {0,0,0,0};
    float arA = 0.f, atA = 0.f, arB = 0.f, atB = 0.f;

#define FETCH_EDGE(I, HV, AR, AT)                                   \
    { int _s; if ((I) < dg) { _s = srcs[off + (I)]; AT = attrs[off + (I)]; } \
      else { _s = n; AT = lattr; }                                   \
      AR = asrc_t[_s * 8 + b];                                       \
      HV = *(const uint4*)(hb + (long)_s * DD + c16 * 8); }

    if (0 < cnt) FETCH_EDGE(0, hvA, arA, atA);
    if (1 < cnt) FETCH_EDGE(1, hvB, arB, atB);

    for (int i = 0; i < cnt; i += 2) {
        uint4 nhA = {0,0,0,0}, nhB = {0,0,0,0};
        float narA = 0.f, natA = 0.f, narB = 0.f, natB = 0.f;
        if (i + 2 < cnt) FETCH_EDGE(i + 2, nhA, narA, natA);
        if (i + 3 < cnt) FETCH_EDGE(i + 3, nhB, narB, natB);
        {
            float a = arA + an + c * atA;
            a = (a > 0.f) ? a : SLOPE * a;
            float ex = __expf(a);
            ssum += ex;
            acc[0] += ex * __uint_as_float(hvA.x << 16);
            acc[1] += ex * __uint_as_float(hvA.x & 0xFFFF0000u);
            acc[2] += ex * __uint_as_float(hvA.y << 16);
            acc[3] += ex * __uint_as_float(hvA.y & 0xFFFF0000u);
            acc[4] += ex * __uint_as_float(hvA.z << 16);
            acc[5] += ex * __uint_as_float(hvA.z & 0xFFFF0000u);
            acc[6] += ex * __uint_as_float(hvA.w << 16);
            acc[7] += ex * __uint_as_float(hvA.w & 0xFFFF0000u);
        }
        if (i + 1 < cnt) {
            float a = arB + an + c * atB;
            a = (a > 0.f) ? a : SLOPE * a;
            float ex = __expf(a);
            ssum += ex;
            acc[0] += ex * __uint_as_float(hvB.x << 16);
            acc[1] += ex * __uint_as_float(hvB.x & 0xFFFF0000u);
            acc[2] += ex * __uint_as_float(hvB.y << 16);
            acc[3] += ex * __uint_as_float(hvB.y & 0xFFFF0000u);
            acc[4] += ex * __uint_as_float(hvB.z << 16);
            acc[5] += ex * __uint_as_float(hvB.z & 0xFFFF0000u);
            acc[6] += ex * __uint_as_float(hvB.w << 16);
            acc[7] += ex * __uint_as_float(hvB.w & 0xFFFF0000u);
        }
        hvA = nhA; arA = narA; atA = natA;
        hvB = nhB; arB = narB; atB = natB;
    }
#undef FETCH_EDGE

    float inv = 1.0f / (ssum + 1e-16f);
    if (c16 == 0) invT[n * 8 + b] = inv;
    #pragma unroll
    for (int j = 0; j < 8; j++) acc[j] = acc[j] * inv + ldf(bias, c16 * 8 + j, f32);

    long row = (long)b * NN + n;
    if (f32) {
        float4 lo = {acc[0], acc[1], acc[2], acc[3]};
        float4 hi = {acc[4], acc[5], acc[6], acc[7]};
        float4* orow = (float4*)((float*)outbuf + row * DD);
        orow[c16 * 2]     = lo;
        orow[c16 * 2 + 1] = hi;
    } else {
        short8 o;
        #pragma unroll
        for (int j = 0; j < 8; j++) o[j] = bf16bits(acc[j]);
        ((short8*)((__hip_bfloat16*)outbuf + row * DD))[c16] = o;
    }
}

// ---------------- attn: edge order; vectorized [n][8] reads, coalesced writes ----------------
__global__ __launch_bounds__(256) void k_attn(const int* __restrict__ ei,
                                              const void* __restrict__ attr,
                                              const float* __restrict__ asrc_t,
                                              const float* __restrict__ adst_t,
                                              const int* __restrict__ deg,
                                              const float* __restrict__ lsum,
                                              const float* __restrict__ cptr,
                                              const float* __restrict__ invT,
                                              const int* __restrict__ flags,
                                              void* __restrict__ outbuf) {
    int f32 = flags[0], i64 = flags[1];
    int e2 = blockIdx.x * 256 + threadIdx.x;
    if (e2 >= EE2) return;
    float c = *cptr;
    int s, d; float at;
    if (e2 < EE) {
        s = esrc(ei, e2, i64);
        d = edst(ei, e2, i64);
        at = ldf(attr, e2, f32);
    } else {
        int nn = e2 - EE;
        s = nn; d = nn;
        at = lsum[nn] / fmaxf((float)deg[nn], 1.0f);
    }
    float4 as0 = *(const float4*)(asrc_t + (long)s * 8);
    float4 as1 = *(const float4*)(asrc_t + (long)s * 8 + 4);
    float4 ad0 = *(const float4*)(adst_t + (long)d * 8);
    float4 ad1 = *(const float4*)(adst_t + (long)d * 8 + 4);
    float4 iv0 = *(const float4*)(invT   + (long)d * 8);
    float4 iv1 = *(const float4*)(invT   + (long)d * 8 + 4);
    float asv[8] = {as0.x, as0.y, as0.z, as0.w, as1.x, as1.y, as1.z, as1.w};
    float adv[8] = {ad0.x, ad0.y, ad0.z, ad0.w, ad1.x, ad1.y, ad1.z, ad1.w};
    float ivv[8] = {iv0.x, iv0.y, iv0.z, iv0.w, iv1.x, iv1.y, iv1.z, iv1.w};
    float ca = c * at;
    #pragma unroll
    for (int b = 0; b < BATCH; b++) {
        float a = asv[b] + adv[b] + ca;
        a = (a > 0.f) ? a : SLOPE * a;
        float al = __expf(a) * ivv[b];
        long gidx = OUT_ELEMS + (long)b * EE2 + e2;
        if (f32) ((float*)outbuf)[gidx] = al;
        else     ((__hip_bfloat16*)outbuf)[gidx] = __float2bfloat16(al);
    }
}

extern "C" void kernel_launch(void* const* d_in, const int* in_sizes, int n_in,
                              void* d_out, int out_size, void* d_ws, size_t ws_size,
                              hipStream_t stream) {
    const void* x        = d_in[0];
    const int*  ei       = (const int*)d_in[1];
    const void* attr     = d_in[2];
    const void* W        = d_in[3];
    const void* We       = d_in[4];
    const void* att_src  = d_in[5];
    const void* att_dst  = d_in[6];
    const void* att_edge = d_in[7];
    const void* bias     = d_in[8];

    char* ws = (char*)d_ws;
    size_t off = 0;
    auto alloc = [&](size_t bytes) { size_t o = off; off = (off + bytes + 255) & ~(size_t)255; return o; };
    __hip_bfloat16* h    = (__hip_bfloat16*)(ws + alloc((size_t)BATCH * NN * DD * 2));
    float* asrc_t        = (float*)(ws + alloc((size_t)NN * 8 * 4));
    float* adst_t        = (float*)(ws + alloc((size_t)NN * 8 * 4));
    float* invT          = (float*)(ws + alloc((size_t)NN * 8 * 4));
    int*   deg           = (int*)  (ws + alloc((size_t)NN * 4));
    float* lsum          = (float*)(ws + alloc((size_t)NN * 4));
    int*   offs          = (int*)  (ws + alloc((size_t)(NN + 1) * 4));
    int*   srcs          = (int*)  (ws + alloc((size_t)EE * 4));
    float* attrs         = (float*)(ws + alloc((size_t)EE * 4));
    __hip_bfloat16* Wb   = (__hip_bfloat16*)(ws + alloc((size_t)DD * DD * 2));
    float* cscal         = (float*)(ws + alloc(256));
    int*   flags         = (int*)  (ws + alloc(256));

    k_detect<<<41, 256, 0, stream>>>((const unsigned short*)x, ei, We, att_edge,
                                     flags, cscal, deg, lsum);
    k_deg   <<<EB + 32, 256, 0, stream>>>(ei, attr, W, flags, deg, lsum, Wb);
    k_gemm  <<<(BATCH * NN) / 32, 128, 0, stream>>>(x, Wb, att_src, att_dst, flags,
                                                    h, asrc_t, adst_t);
    k_scan  <<<1, 1024, 0, stream>>>(deg, offs);
    k_fill  <<<EB, 256, 0, stream>>>(ei, attr, flags, offs, srcs, attrs);
    k_agg   <<<(BATCH * NN) / 16, 256, 0, stream>>>(srcs, attrs, asrc_t, adst_t, h,
                                                    deg, lsum, offs, cscal, bias, flags,
                                                    invT, d_out);
    k_attn  <<<(EE2 + 255) / 256, 256, 0, stream>>>(ei, attr, asrc_t, adst_t, deg, lsum,
                                                    cscal, invT, flags, d_out);
}